// Round 25
// baseline (185.181 us; speedup 1.0000x reference)
//
#include <hip/hip_runtime.h>
#include <hip/hip_bf16.h>

#define S_LEN 2048
#define NHEAD 16
#define HDIM 64
#define HID 1024

typedef __attribute__((ext_vector_type(8))) short bf16x8;
typedef __attribute__((ext_vector_type(4))) float f32x4;
typedef __attribute__((ext_vector_type(4))) unsigned int u32x4;
typedef __attribute__((ext_vector_type(2))) unsigned int u32x2;

__device__ __forceinline__ unsigned short f2bf(float x) {
    unsigned int u = __builtin_bit_cast(unsigned int, x);
    u = (u + 0x7fffu + ((u >> 16) & 1u)) >> 16;
    return (unsigned short)u;
}
__device__ __forceinline__ float bf2f(unsigned short s) {
    unsigned int u = ((unsigned int)s) << 16;
    return __builtin_bit_cast(float, u);
}
__device__ __forceinline__ unsigned cvtpk_bf16(float lo, float hi) {
    unsigned r;
    asm("v_cvt_pk_bf16_f32 %0, %1, %2" : "=v"(r) : "v"(lo), "v"(hi));
    return r;
}
__device__ __forceinline__ void gload16(const short* g, short* l) {
    __builtin_amdgcn_global_load_lds(
        (const __attribute__((address_space(1))) unsigned int*)g,
        (__attribute__((address_space(3))) unsigned int*)l, 16, 0, 0);
}
__device__ __forceinline__ bf16x8 negbf8(bf16x8 v) {
    u32x4 u = __builtin_bit_cast(u32x4, v);
    #pragma unroll
    for (int e = 0; e < 4; e++) u[e] ^= 0x80008000u;
    return __builtin_bit_cast(bf16x8, u);
}

// scale folded into Q: scores arrive as flow*log2(e) -> softmax via exp2
#define QSCALE 0.1803368801111168f   // 0.125 * log2(e)

// ---------------- prep: f32 -> bf16 convert (vectorized) ----------------
__global__ void cvt_kernel(const float* __restrict__ src, short* __restrict__ dst, int n4) {
    int i = blockIdx.x * blockDim.x + threadIdx.x;
    if (i < n4) {
        float4 v = reinterpret_cast<const float4*>(src)[i];
        short4 o;
        o.x = (short)f2bf(v.x); o.y = (short)f2bf(v.y);
        o.z = (short)f2bf(v.z); o.w = (short)f2bf(v.w);
        reinterpret_cast<short4*>(dst)[i] = o;
    }
}

// ------------- prep: all 4 weight transposes in ONE launch ----------------
__global__ void transpose_all(const float* __restrict__ Wq, const float* __restrict__ Wk,
                              const float* __restrict__ Wv, const float* __restrict__ Wg,
                              short* __restrict__ WT, short* __restrict__ WgT) {
    __shared__ float tile[32][33];
    int z = blockIdx.z;
    const float* src; short* dst; int R;
    if (z == 0)      { src = Wq; dst = WT;               R = 1024; }
    else if (z == 1) { src = Wk; dst = WT + 1024 * 1024; R = 1024; }
    else if (z == 2) { src = Wv; dst = WT + 2 * 1024 * 1024; R = 1024; }
    else             { src = Wg; dst = WgT;              R = 2048; }
    int by = blockIdx.y * 32;
    if (by >= R) return;
    int bx = blockIdx.x * 32;
    const int C = 1024;
    int tx = threadIdx.x, ty = threadIdx.y;  // 32 x 8
    #pragma unroll
    for (int i = ty; i < 32; i += 8)
        tile[i][tx] = src[(size_t)(by + i) * C + bx + tx];
    __syncthreads();
    #pragma unroll
    for (int i = ty; i < 32; i += 8)
        dst[(size_t)(bx + i) * R + by + tx] = (short)f2bf(tile[tx][i]);
}

// ---------------- QKV GEMM: [4096,1024] @ [1024,3072] -------------------
// 128x128 tile, grid (32,24); BK=64 two-half LDS. V output written DIRECTLY
// transposed into VT (j-values are consecutive s -> contiguous short4).
__global__ __launch_bounds__(256, 2)
void gemm_qkv(const short* __restrict__ xb, const short* __restrict__ WT,
              const float* __restrict__ bq, const float* __restrict__ bk,
              const float* __restrict__ bv,
              short* __restrict__ Qb, short* __restrict__ Kb, short* __restrict__ VT) {
    __shared__ short Al[2][128 * 32];
    __shared__ short Bl[2][128 * 32];
    int mb = blockIdx.x, nb = blockIdx.y;
    int tid = threadIdx.x;
    int wave = tid >> 6, lane = tid & 63;
    int wm = wave >> 1, wn = wave & 1;
    int lr = lane & 15, lg = lane >> 4;

    int r = tid >> 2;
    int c = tid & 3;
    int sc = (c ^ (r & 3)) * 8;
    int dst0 = tid * 8;
    int dst1 = (tid + 256) * 8;
    const short* a0 = xb + (size_t)(mb * 128 + r) * 1024 + sc;
    const short* a1 = a0 + (size_t)64 * 1024;
    const short* b0 = WT + (size_t)(nb * 128 + r) * 1024 + sc;
    const short* b1 = b0 + (size_t)64 * 1024;
    int fsw = (lg ^ (lr & 3)) * 8;

    f32x4 acc[4][4] = {};

    for (int ks = 0; ks < 16; ++ks) {
        int kg = ks * 64;
        __syncthreads();
        gload16(a0 + kg,      &Al[0][dst0]);
        gload16(a1 + kg,      &Al[0][dst1]);
        gload16(a0 + kg + 32, &Al[1][dst0]);
        gload16(a1 + kg + 32, &Al[1][dst1]);
        gload16(b0 + kg,      &Bl[0][dst0]);
        gload16(b1 + kg,      &Bl[0][dst1]);
        gload16(b0 + kg + 32, &Bl[1][dst0]);
        gload16(b1 + kg + 32, &Bl[1][dst1]);
        __syncthreads();
        #pragma unroll
        for (int s = 0; s < 2; s++) {
            bf16x8 af[4], bfr[4];
            #pragma unroll
            for (int t = 0; t < 4; t++)
                af[t] = *(bf16x8*)&Al[s][(wm * 64 + t * 16 + lr) * 32 + fsw];
            #pragma unroll
            for (int t = 0; t < 4; t++)
                bfr[t] = *(bf16x8*)&Bl[s][(wn * 64 + t * 16 + lr) * 32 + fsw];
            #pragma unroll
            for (int i = 0; i < 4; i++)
                #pragma unroll
                for (int jn = 0; jn < 4; jn++)
                    acc[i][jn] = __builtin_amdgcn_mfma_f32_16x16x32_bf16(af[i], bfr[jn], acc[i][jn], 0, 0, 0);
        }
    }

    int which = (nb * 128) >> 10;
    #pragma unroll
    for (int jn = 0; jn < 4; jn++) {
        int n = nb * 128 + wn * 64 + jn * 16 + lr;
        int n1 = n & 1023;
        if (which < 2) {
            const float* bias = (which == 0) ? bq : bk;
            short* out = (which == 0) ? Qb : Kb;
            float scale = (which == 0) ? QSCALE : 1.0f;
            float bv_ = bias[n1];
            #pragma unroll
            for (int i = 0; i < 4; i++) {
                #pragma unroll
                for (int j = 0; j < 4; j++) {
                    int mm = mb * 128 + wm * 64 + i * 16 + lg * 4 + j;
                    out[(size_t)mm * 1024 + n1] = (short)f2bf(acc[i][jn][j] * scale + bv_ * scale);
                }
            }
        } else {
            int h = n1 >> 6, dv = n1 & 63;
            float bv_ = bv[n1];
            #pragma unroll
            for (int i = 0; i < 4; i++) {
                int mm0 = mb * 128 + wm * 64 + i * 16 + lg * 4;
                int bb = mm0 >> 11, ss = mm0 & 2047;
                short4 vvv;
                vvv.x = (short)f2bf(acc[i][jn][0] + bv_);
                vvv.y = (short)f2bf(acc[i][jn][1] + bv_);
                vvv.z = (short)f2bf(acc[i][jn][2] + bv_);
                vvv.w = (short)f2bf(acc[i][jn][3] + bv_);
                *(short4*)&VT[((size_t)((bb * 16 + h) * 64 + dv)) * S_LEN + ss] = vvv;
            }
        }
    }
}

// ---------------- flash attention with antisymmetric flow ---------------
// r22 structure + Kt/Qt DOUBLE-BUFFERED: the 6 ds_writes per tile now issue
// at tile top and drain UNDER the S-MFMA cluster (previously they sat
// serially between the two barriers). Same 2 barriers/tile; Vt stays single
// buffered (written & read within one tile). LDS 48KB -> 3 blocks/CU (~= the
// measured 2.8 occupancy, so no TLP loss).
__global__ __launch_bounds__(256, 4)
void attn_kernel(const short* __restrict__ Qb, const short* __restrict__ Kb,
                 const short* __restrict__ VT, short* __restrict__ Fb) {
    __shared__ short Kt[2][64 * 64];
    __shared__ short Qt[2][64 * 64];
    __shared__ short Vt[64 * 64];
    __shared__ short Pl[4][16 * 64];

    int bid = (blockIdx.x & 7) * 128 + (blockIdx.x >> 3);   // T1 swizzle
    int qb = bid & 31;
    int bh = bid >> 5;
    int b = bh >> 4, h = bh & 15;
    int tid = threadIdx.x;
    int wave = tid >> 6, lane = tid & 63;
    int lr = lane & 15, lg = lane >> 4;

    size_t rowbase = ((size_t)(b * S_LEN + qb * 64 + wave * 16 + lr)) * HID + h * HDIM;
    bf16x8 Qf[2], Kf[2];
    #pragma unroll
    for (int cc = 0; cc < 2; cc++) {
        Qf[cc] = *(const bf16x8*)(Qb + rowbase + cc * 32 + lg * 8);
        Kf[cc] = negbf8(*(const bf16x8*)(Kb + rowbase + cc * 32 + lg * 8));
    }

    int r0 = tid >> 3;
    int c = tid & 7;
    int swz = (c ^ (r0 & 7)) * 8;
    int dst0 = r0 * 64 + swz;
    int dst1 = (r0 + 32) * 64 + swz;
    const short* kp = Kb + (size_t)(b * S_LEN + r0) * HID + h * HDIM + c * 8;
    const short* qp = Qb + (size_t)(b * S_LEN + r0) * HID + h * HDIM + c * 8;
    const short* vp = VT + (size_t)bh * HDIM * S_LEN + (size_t)r0 * S_LEN + c * 8;

    // prologue: tile0 K/Q -> Kt[0]/Qt[0]; regs then hold tile1 K/Q, tile0 V
    bf16x8 kv0 = *(const bf16x8*)kp;
    bf16x8 kv1 = *(const bf16x8*)(kp + 32 * HID);
    bf16x8 qv0 = *(const bf16x8*)qp;
    bf16x8 qv1 = *(const bf16x8*)(qp + 32 * HID);
    bf16x8 vv0 = *(const bf16x8*)vp;
    bf16x8 vv1 = *(const bf16x8*)(vp + 32 * S_LEN);
    *(bf16x8*)&Kt[0][dst0] = kv0;
    *(bf16x8*)&Kt[0][dst1] = kv1;
    *(bf16x8*)&Qt[0][dst0] = qv0;
    *(bf16x8*)&Qt[0][dst1] = qv1;
    kp += 64 * HID; qp += 64 * HID; vp += 64;
    kv0 = *(const bf16x8*)kp;
    kv1 = *(const bf16x8*)(kp + 32 * HID);
    qv0 = *(const bf16x8*)qp;
    qv1 = *(const bf16x8*)(qp + 32 * HID);
    kp += 64 * HID; qp += 64 * HID;          // kp/qp now point at tile 2

    f32x4 O[4] = {};
    float m = -1e30f, l = 0.f;
    int pb = 0;

    __syncthreads();                          // Kt[0]/Qt[0] visible

    for (int kt = 0; kt < 32; ++kt) {
        // writes drain under S-MFMA: Vt(t), Kt/Qt[pb^1](t+1)
        *(bf16x8*)&Vt[dst0] = vv0;
        *(bf16x8*)&Vt[dst1] = vv1;
        *(bf16x8*)&Kt[pb ^ 1][dst0] = kv0;
        *(bf16x8*)&Kt[pb ^ 1][dst1] = kv1;
        *(bf16x8*)&Qt[pb ^ 1][dst0] = qv0;
        *(bf16x8*)&Qt[pb ^ 1][dst1] = qv1;

        f32x4 S[4] = {};
        __builtin_amdgcn_s_setprio(1);
        #pragma unroll
        for (int t = 0; t < 4; t++) {
            #pragma unroll
            for (int c2 = 0; c2 < 2; c2++) {
                int fo = (t * 16 + lr) * 64 + (((4 * c2 + lg) ^ (lr & 7)) * 8);
                bf16x8 kf = *(bf16x8*)&Kt[pb][fo];
                bf16x8 qf = *(bf16x8*)&Qt[pb][fo];
                S[t] = __builtin_amdgcn_mfma_f32_16x16x32_bf16(kf, Qf[c2], S[t], 0, 0, 0);
                S[t] = __builtin_amdgcn_mfma_f32_16x16x32_bf16(qf, Kf[c2], S[t], 0, 0, 0);
            }
        }
        __builtin_amdgcn_s_setprio(0);

        // prefetch: vv(t+1), kv/qv(t+2) — overlaps softmax + PV
        vv0 = *(const bf16x8*)vp;
        vv1 = *(const bf16x8*)(vp + 32 * S_LEN);
        vp += 64;
        kv0 = *(const bf16x8*)kp;
        kv1 = *(const bf16x8*)(kp + 32 * HID);
        qv0 = *(const bf16x8*)qp;
        qv1 = *(const bf16x8*)(qp + 32 * HID);
        kp += 64 * HID; qp += 64 * HID;

        float pm = -1e30f;
        #pragma unroll
        for (int t = 0; t < 4; t++)
            #pragma unroll
            for (int j = 0; j < 4; j++) pm = fmaxf(pm, S[t][j]);
        pm = fmaxf(pm, __shfl_xor(pm, 16));
        pm = fmaxf(pm, __shfl_xor(pm, 32));

        if (__any(pm > m + 8.f)) {
            float mn = fmaxf(m, pm);
            float alpha = exp2f(m - mn);
            m = mn;
            l *= alpha;
            float a[4];
            #pragma unroll
            for (int j = 0; j < 4; j++) a[j] = __shfl(alpha, lg * 4 + j);
            #pragma unroll
            for (int dvt = 0; dvt < 4; dvt++)
                #pragma unroll
                for (int j = 0; j < 4; j++) O[dvt][j] *= a[j];
        }

        unsigned Pd[4][2];
        float rs = 0.f;
        #pragma unroll
        for (int t = 0; t < 4; t++) {
            float p0 = exp2f(S[t][0] - m);
            float p1 = exp2f(S[t][1] - m);
            float p2 = exp2f(S[t][2] - m);
            float p3 = exp2f(S[t][3] - m);
            rs += (p0 + p1) + (p2 + p3);
            Pd[t][0] = cvtpk_bf16(p0, p1);
            Pd[t][1] = cvtpk_bf16(p2, p3);
        }
        rs += __shfl_xor(rs, 16);
        rs += __shfl_xor(rs, 32);
        l += rs;
        #pragma unroll
        for (int t = 0; t < 4; t++) {
            u32x2 pw;
            pw[0] = Pd[t][0];
            pw[1] = Pd[t][1];
            int po = lr * 64 + (((2 * t + (lg >> 1)) ^ (lr & 7)) * 8) + (lg & 1) * 4;
            *(u32x2*)&Pl[wave][po] = pw;
        }

        __syncthreads();                       // B: Vt(t) visible

        __builtin_amdgcn_s_setprio(1);
        #pragma unroll
        for (int c2 = 0; c2 < 2; c2++) {
            bf16x8 pf = *(bf16x8*)&Pl[wave][lr * 64 + (((4 * c2 + lg) ^ (lr & 7)) * 8)];
            #pragma unroll
            for (int dvt = 0; dvt < 4; dvt++) {
                bf16x8 vf = *(bf16x8*)&Vt[(dvt * 16 + lr) * 64 + (((4 * c2 + lg) ^ (lr & 7)) * 8)];
                O[dvt] = __builtin_amdgcn_mfma_f32_16x16x32_bf16(pf, vf, O[dvt], 0, 0, 0);
            }
        }
        __builtin_amdgcn_s_setprio(0);

        __syncthreads();                       // A: PV done -> Vt/Kt[pb] reusable
        pb ^= 1;
    }

    float linv = 1.f / l;
    float li[4];
    #pragma unroll
    for (int j = 0; j < 4; j++) li[j] = __shfl(linv, lg * 4 + j);
    #pragma unroll
    for (int dvt = 0; dvt < 4; dvt++) {
        #pragma unroll
        for (int j = 0; j < 4; j++) {
            int q = qb * 64 + wave * 16 + lg * 4 + j;
            int dv = dvt * 16 + lr;
            Fb[((size_t)(b * S_LEN + q)) * HID + h * HDIM + dv] =
                (short)f2bf(O[dvt][j] * li[j]);
        }
    }
}

// ------- gate GEMM (K=2048 over [xb | flowed]) + sigmoid + residual -----
// 64x64 tile, grid (64,16) = 1024 blocks = 4 blocks/CU; BK=64.
__global__ __launch_bounds__(256, 4)
void gemm_gate(const short* __restrict__ xb, const short* __restrict__ fb,
               const short* __restrict__ WgT, const float* __restrict__ bg,
               const float* __restrict__ x, float* __restrict__ y) {
    __shared__ short Al[2][64 * 32];
    __shared__ short Bl[2][64 * 32];
    int mb = blockIdx.x, nb = blockIdx.y;
    int tid = threadIdx.x;
    int wave = tid >> 6, lane = tid & 63;
    int wm = wave >> 1, wn = wave & 1;
    int lr = lane & 15, lg = lane >> 4;

    int r = tid >> 2;
    int c = tid & 3;
    int sc = (c ^ (r & 3)) * 8;
    int dst0 = tid * 8;
    size_t arow = (size_t)(mb * 64 + r) * 1024 + sc;
    const short* b0 = WgT + (size_t)(nb * 64 + r) * 2048 + sc;
    int fsw = (lg ^ (lr & 3)) * 8;

    f32x4 acc[2][2] = {};

    for (int ks = 0; ks < 32; ++ks) {
        int kg = ks * 64;
        const short* A = (kg < 1024) ? (xb + kg) : (fb + (kg - 1024));
        __syncthreads();
        gload16(A + arow, &Al[0][dst0]);
        gload16(A + arow + 32, &Al[1][dst0]);
        gload16(b0 + kg, &Bl[0][dst0]);
        gload16(b0 + kg + 32, &Bl[1][dst0]);
        __syncthreads();
        bf16x8 af[2][2], bfr[2][2];
        #pragma unroll
        for (int t = 0; t < 2; t++)
            #pragma unroll
            for (int s = 0; s < 2; s++) {
                af[t][s]  = *(bf16x8*)&Al[s][(wm * 32 + t * 16 + lr) * 32 + fsw];
                bfr[t][s] = *(bf16x8*)&Bl[s][(wn * 32 + t * 16 + lr) * 32 + fsw];
            }
        #pragma unroll
        for (int i = 0; i < 2; i++)
            #pragma unroll
            for (int jn = 0; jn < 2; jn++)
                #pragma unroll
                for (int s = 0; s < 2; s++)
                    acc[i][jn] = __builtin_amdgcn_mfma_f32_16x16x32_bf16(af[i][s], bfr[jn][s], acc[i][jn], 0, 0, 0);
    }

    #pragma unroll
    for (int jn = 0; jn < 2; jn++) {
        int n = nb * 64 + wn * 32 + jn * 16 + lr;
        float bgv = bg[n];
        #pragma unroll
        for (int i = 0; i < 2; i++) {
            #pragma unroll
            for (int j = 0; j < 4; j++) {
                int mm = mb * 64 + wm * 32 + i * 16 + lg * 4 + j;
                size_t idx = (size_t)mm * 1024 + n;
                float z = acc[i][jn][j] + bgv;
                float gate = 1.f / (1.f + __expf(-z));
                float fv = bf2f((unsigned short)fb[idx]);
                y[idx] = x[idx] + gate * fv;
            }
        }
    }
}

// ---------------- row LayerNorm in place (fp32 -> fp32) ----------------
__global__ __launch_bounds__(256)
void ln_kernel(float* __restrict__ y, const float* __restrict__ gamma,
               const float* __restrict__ beta) {
    int row = blockIdx.x;
    int tid = threadIdx.x;
    float4 v4 = *(const float4*)&y[(size_t)row * 1024 + tid * 4];
    float v[4] = {v4.x, v4.y, v4.z, v4.w};
    float s = v[0] + v[1] + v[2] + v[3];
    float s2 = v[0]*v[0] + v[1]*v[1] + v[2]*v[2] + v[3]*v[3];
    #pragma unroll
    for (int off = 1; off < 64; off <<= 1) {
        s += __shfl_xor(s, off);
        s2 += __shfl_xor(s2, off);
    }
    __shared__ float red[8];
    int wave = tid >> 6, lane = tid & 63;
    if (lane == 0) { red[wave] = s; red[4 + wave] = s2; }
    __syncthreads();
    s = red[0] + red[1] + red[2] + red[3];
    s2 = red[4] + red[5] + red[6] + red[7];
    float mu = s * (1.f / 1024.f);
    float var = s2 * (1.f / 1024.f) - mu * mu;
    float rsq = rsqrtf(var + 1e-5f);
    float4 o4;
    float* o = (float*)&o4;
    #pragma unroll
    for (int e = 0; e < 4; e++) {
        int n = tid * 4 + e;
        o[e] = (v[e] - mu) * rsq * gamma[n] + beta[n];
    }
    *(float4*)&y[(size_t)row * 1024 + tid * 4] = o4;
}

extern "C" void kernel_launch(void* const* d_in, const int* in_sizes, int n_in,
                              void* d_out, int out_size, void* d_ws, size_t ws_size,
                              hipStream_t stream) {
    const float* x     = (const float*)d_in[0];
    const float* Wq    = (const float*)d_in[1];
    const float* bq    = (const float*)d_in[2];
    const float* Wk    = (const float*)d_in[3];
    const float* bk    = (const float*)d_in[4];
    const float* Wv    = (const float*)d_in[5];
    const float* bv    = (const float*)d_in[6];
    const float* Wg    = (const float*)d_in[7];
    const float* bg    = (const float*)d_in[8];
    const float* gamma = (const float*)d_in[9];
    const float* beta  = (const float*)d_in[10];
    float* out = (float*)d_out;   // reference output is fp32

    char* w = (char*)d_ws;
    const size_t MB = 1024 * 1024;
    short* xb  = (short*)(w + 0 * MB);    // [4096][1024] bf16
    short* Qb  = (short*)(w + 8 * MB);    // pre-scaled by QSCALE
    short* Kb  = (short*)(w + 16 * MB);
    short* WT  = (short*)(w + 32 * MB);   // [3072][1024] bf16 (Wq^T|Wk^T|Wv^T)
    short* WgT = (short*)(w + 38 * MB);   // [1024][2048] bf16
    short* fb  = (short*)(w + 42 * MB);   // flowed bf16 [4096][1024]
    short* VT  = (short*)(w + 50 * MB);   // V^T per head [b*16+h][64 dv][2048 s]

    cvt_kernel<<<4096, 256, 0, stream>>>(x, xb, 4096 * 1024 / 4);
    dim3 tb(32, 8);
    transpose_all<<<dim3(32, 64, 4), tb, 0, stream>>>(Wq, Wk, Wv, Wg, WT, WgT);
    gemm_qkv<<<dim3(32, 24), 256, 0, stream>>>(xb, WT, bq, bk, bv, Qb, Kb, VT);
    attn_kernel<<<1024, 256, 0, stream>>>(Qb, Kb, VT, fb);
    gemm_gate<<<dim3(64, 16), 256, 0, stream>>>(xb, fb, WgT, bg, x, out);
    ln_kernel<<<4096, 256, 0, stream>>>(out, gamma, beta);
}

// Round 26
// 170.922 us; speedup vs baseline: 1.0834x; 1.0834x over previous
//
#include <hip/hip_runtime.h>
#include <hip/hip_bf16.h>

#define S_LEN 2048
#define NHEAD 16
#define HDIM 64
#define HID 1024

typedef __attribute__((ext_vector_type(8))) short bf16x8;
typedef __attribute__((ext_vector_type(4))) float f32x4;
typedef __attribute__((ext_vector_type(4))) unsigned int u32x4;
typedef __attribute__((ext_vector_type(2))) unsigned int u32x2;

__device__ __forceinline__ unsigned short f2bf(float x) {
    unsigned int u = __builtin_bit_cast(unsigned int, x);
    u = (u + 0x7fffu + ((u >> 16) & 1u)) >> 16;
    return (unsigned short)u;
}
__device__ __forceinline__ float bf2f(unsigned short s) {
    unsigned int u = ((unsigned int)s) << 16;
    return __builtin_bit_cast(float, u);
}
__device__ __forceinline__ unsigned cvtpk_bf16(float lo, float hi) {
    unsigned r;
    asm("v_cvt_pk_bf16_f32 %0, %1, %2" : "=v"(r) : "v"(lo), "v"(hi));
    return r;
}
__device__ __forceinline__ void gload16(const short* g, short* l) {
    __builtin_amdgcn_global_load_lds(
        (const __attribute__((address_space(1))) unsigned int*)g,
        (__attribute__((address_space(3))) unsigned int*)l, 16, 0, 0);
}
__device__ __forceinline__ bf16x8 negbf8(bf16x8 v) {
    u32x4 u = __builtin_bit_cast(u32x4, v);
    #pragma unroll
    for (int e = 0; e < 4; e++) u[e] ^= 0x80008000u;
    return __builtin_bit_cast(bf16x8, u);
}

// scale folded into Q: scores arrive as flow*log2(e) -> softmax via exp2
#define QSCALE 0.1803368801111168f   // 0.125 * log2(e)

// ---------------- prep: f32 -> bf16 convert (vectorized) ----------------
__global__ void cvt_kernel(const float* __restrict__ src, short* __restrict__ dst, int n4) {
    int i = blockIdx.x * blockDim.x + threadIdx.x;
    if (i < n4) {
        float4 v = reinterpret_cast<const float4*>(src)[i];
        short4 o;
        o.x = (short)f2bf(v.x); o.y = (short)f2bf(v.y);
        o.z = (short)f2bf(v.z); o.w = (short)f2bf(v.w);
        reinterpret_cast<short4*>(dst)[i] = o;
    }
}

// ------------- prep: all 4 weight transposes in ONE launch ----------------
__global__ void transpose_all(const float* __restrict__ Wq, const float* __restrict__ Wk,
                              const float* __restrict__ Wv, const float* __restrict__ Wg,
                              short* __restrict__ WT, short* __restrict__ WgT) {
    __shared__ float tile[32][33];
    int z = blockIdx.z;
    const float* src; short* dst; int R;
    if (z == 0)      { src = Wq; dst = WT;               R = 1024; }
    else if (z == 1) { src = Wk; dst = WT + 1024 * 1024; R = 1024; }
    else if (z == 2) { src = Wv; dst = WT + 2 * 1024 * 1024; R = 1024; }
    else             { src = Wg; dst = WgT;              R = 2048; }
    int by = blockIdx.y * 32;
    if (by >= R) return;
    int bx = blockIdx.x * 32;
    const int C = 1024;
    int tx = threadIdx.x, ty = threadIdx.y;  // 32 x 8
    #pragma unroll
    for (int i = ty; i < 32; i += 8)
        tile[i][tx] = src[(size_t)(by + i) * C + bx + tx];
    __syncthreads();
    #pragma unroll
    for (int i = ty; i < 32; i += 8)
        dst[(size_t)(bx + i) * R + by + tx] = (short)f2bf(tile[tx][i]);
}

// ---------------- QKV GEMM: [4096,1024] @ [1024,3072] -------------------
// 128x128 tile, grid (32,24); BK=64 two-half LDS. V output written DIRECTLY
// transposed into VT (j-values are consecutive s -> contiguous short4),
// eliminating the separate vtrans kernel and the Vb round-trip.
__global__ __launch_bounds__(256, 2)
void gemm_qkv(const short* __restrict__ xb, const short* __restrict__ WT,
              const float* __restrict__ bq, const float* __restrict__ bk,
              const float* __restrict__ bv,
              short* __restrict__ Qb, short* __restrict__ Kb, short* __restrict__ VT) {
    __shared__ short Al[2][128 * 32];
    __shared__ short Bl[2][128 * 32];
    int mb = blockIdx.x, nb = blockIdx.y;
    int tid = threadIdx.x;
    int wave = tid >> 6, lane = tid & 63;
    int wm = wave >> 1, wn = wave & 1;
    int lr = lane & 15, lg = lane >> 4;

    int r = tid >> 2;
    int c = tid & 3;
    int sc = (c ^ (r & 3)) * 8;
    int dst0 = tid * 8;
    int dst1 = (tid + 256) * 8;
    const short* a0 = xb + (size_t)(mb * 128 + r) * 1024 + sc;
    const short* a1 = a0 + (size_t)64 * 1024;
    const short* b0 = WT + (size_t)(nb * 128 + r) * 1024 + sc;
    const short* b1 = b0 + (size_t)64 * 1024;
    int fsw = (lg ^ (lr & 3)) * 8;

    f32x4 acc[4][4] = {};

    for (int ks = 0; ks < 16; ++ks) {
        int kg = ks * 64;
        __syncthreads();
        gload16(a0 + kg,      &Al[0][dst0]);
        gload16(a1 + kg,      &Al[0][dst1]);
        gload16(a0 + kg + 32, &Al[1][dst0]);
        gload16(a1 + kg + 32, &Al[1][dst1]);
        gload16(b0 + kg,      &Bl[0][dst0]);
        gload16(b1 + kg,      &Bl[0][dst1]);
        gload16(b0 + kg + 32, &Bl[1][dst0]);
        gload16(b1 + kg + 32, &Bl[1][dst1]);
        __syncthreads();
        #pragma unroll
        for (int s = 0; s < 2; s++) {
            bf16x8 af[4], bfr[4];
            #pragma unroll
            for (int t = 0; t < 4; t++)
                af[t] = *(bf16x8*)&Al[s][(wm * 64 + t * 16 + lr) * 32 + fsw];
            #pragma unroll
            for (int t = 0; t < 4; t++)
                bfr[t] = *(bf16x8*)&Bl[s][(wn * 64 + t * 16 + lr) * 32 + fsw];
            #pragma unroll
            for (int i = 0; i < 4; i++)
                #pragma unroll
                for (int jn = 0; jn < 4; jn++)
                    acc[i][jn] = __builtin_amdgcn_mfma_f32_16x16x32_bf16(af[i], bfr[jn], acc[i][jn], 0, 0, 0);
        }
    }

    // which (0=Q,1=K,2=V) is uniform per block: 128 | 1024
    int which = (nb * 128) >> 10;
    #pragma unroll
    for (int jn = 0; jn < 4; jn++) {
        int n = nb * 128 + wn * 64 + jn * 16 + lr;
        int n1 = n & 1023;
        if (which < 2) {
            const float* bias = (which == 0) ? bq : bk;
            short* out = (which == 0) ? Qb : Kb;
            float scale = (which == 0) ? QSCALE : 1.0f;
            float bv_ = bias[n1];
            #pragma unroll
            for (int i = 0; i < 4; i++) {
                #pragma unroll
                for (int j = 0; j < 4; j++) {
                    int mm = mb * 128 + wm * 64 + i * 16 + lg * 4 + j;
                    out[(size_t)mm * 1024 + n1] = (short)f2bf(acc[i][jn][j] * scale + bv_ * scale);
                }
            }
        } else {
            // direct transposed store: VT[(b*16+h)*64+dv][s], s=mm (4 consecutive)
            int h = n1 >> 6, dv = n1 & 63;
            float bv_ = bv[n1];
            #pragma unroll
            for (int i = 0; i < 4; i++) {
                int mm0 = mb * 128 + wm * 64 + i * 16 + lg * 4;
                int bb = mm0 >> 11, ss = mm0 & 2047;
                short4 vvv;
                vvv.x = (short)f2bf(acc[i][jn][0] + bv_);
                vvv.y = (short)f2bf(acc[i][jn][1] + bv_);
                vvv.z = (short)f2bf(acc[i][jn][2] + bv_);
                vvv.w = (short)f2bf(acc[i][jn][3] + bv_);
                *(short4*)&VT[((size_t)((bb * 16 + h) * 64 + dv)) * S_LEN + ss] = vvv;
            }
        }
    }
}

// ---------------- flash attention with antisymmetric flow ---------------
// r9/r16 known-good structure + T1 XCD swizzle (head-local L2).
__global__ __launch_bounds__(256, 4)
void attn_kernel(const short* __restrict__ Qb, const short* __restrict__ Kb,
                 const short* __restrict__ VT, short* __restrict__ Fb) {
    __shared__ short Kt[64 * 64];
    __shared__ short Qt[64 * 64];
    __shared__ short Vt[64 * 64];
    __shared__ short Pl[4][16 * 64];

    int bid = (blockIdx.x & 7) * 128 + (blockIdx.x >> 3);   // T1 swizzle
    int qb = bid & 31;
    int bh = bid >> 5;
    int b = bh >> 4, h = bh & 15;
    int tid = threadIdx.x;
    int wave = tid >> 6, lane = tid & 63;
    int lr = lane & 15, lg = lane >> 4;

    size_t rowbase = ((size_t)(b * S_LEN + qb * 64 + wave * 16 + lr)) * HID + h * HDIM;
    bf16x8 Qf[2], Kf[2];
    #pragma unroll
    for (int cc = 0; cc < 2; cc++) {
        Qf[cc] = *(const bf16x8*)(Qb + rowbase + cc * 32 + lg * 8);
        Kf[cc] = negbf8(*(const bf16x8*)(Kb + rowbase + cc * 32 + lg * 8));
    }

    int r0 = tid >> 3;
    int c = tid & 7;
    int swz = (c ^ (r0 & 7)) * 8;
    int dst0 = r0 * 64 + swz;
    int dst1 = (r0 + 32) * 64 + swz;
    const short* kp = Kb + (size_t)(b * S_LEN + r0) * HID + h * HDIM + c * 8;
    const short* qp = Qb + (size_t)(b * S_LEN + r0) * HID + h * HDIM + c * 8;
    const short* vp = VT + (size_t)bh * HDIM * S_LEN + (size_t)r0 * S_LEN + c * 8;

    bf16x8 kv0 = *(const bf16x8*)kp;
    bf16x8 kv1 = *(const bf16x8*)(kp + 32 * HID);
    bf16x8 qv0 = *(const bf16x8*)qp;
    bf16x8 qv1 = *(const bf16x8*)(qp + 32 * HID);
    bf16x8 vv0 = *(const bf16x8*)vp;
    bf16x8 vv1 = *(const bf16x8*)(vp + 32 * S_LEN);
    kp += 64 * HID; qp += 64 * HID; vp += 64;

    f32x4 O[4] = {};
    float m = -1e30f, l = 0.f;

    for (int kt = 0; kt < 32; ++kt) {
        __syncthreads();
        *(bf16x8*)&Kt[dst0] = kv0;
        *(bf16x8*)&Kt[dst1] = kv1;
        *(bf16x8*)&Qt[dst0] = qv0;
        *(bf16x8*)&Qt[dst1] = qv1;
        *(bf16x8*)&Vt[dst0] = vv0;
        *(bf16x8*)&Vt[dst1] = vv1;
        __syncthreads();

        if (kt < 31) {
            kv0 = *(const bf16x8*)kp;
            kv1 = *(const bf16x8*)(kp + 32 * HID);
            qv0 = *(const bf16x8*)qp;
            qv1 = *(const bf16x8*)(qp + 32 * HID);
            vv0 = *(const bf16x8*)vp;
            vv1 = *(const bf16x8*)(vp + 32 * S_LEN);
            kp += 64 * HID; qp += 64 * HID; vp += 64;
        }

        f32x4 S[4] = {};
        __builtin_amdgcn_s_setprio(1);
        #pragma unroll
        for (int t = 0; t < 4; t++) {
            #pragma unroll
            for (int c2 = 0; c2 < 2; c2++) {
                int fo = (t * 16 + lr) * 64 + (((4 * c2 + lg) ^ (lr & 7)) * 8);
                bf16x8 kf = *(bf16x8*)&Kt[fo];
                bf16x8 qf = *(bf16x8*)&Qt[fo];
                S[t] = __builtin_amdgcn_mfma_f32_16x16x32_bf16(kf, Qf[c2], S[t], 0, 0, 0);
                S[t] = __builtin_amdgcn_mfma_f32_16x16x32_bf16(qf, Kf[c2], S[t], 0, 0, 0);
            }
        }
        __builtin_amdgcn_s_setprio(0);

        float pm = -1e30f;
        #pragma unroll
        for (int t = 0; t < 4; t++)
            #pragma unroll
            for (int j = 0; j < 4; j++) pm = fmaxf(pm, S[t][j]);
        pm = fmaxf(pm, __shfl_xor(pm, 16));
        pm = fmaxf(pm, __shfl_xor(pm, 32));

        if (__any(pm > m + 8.f)) {
            float mn = fmaxf(m, pm);
            float alpha = exp2f(m - mn);
            m = mn;
            l *= alpha;
            float a[4];
            #pragma unroll
            for (int j = 0; j < 4; j++) a[j] = __shfl(alpha, lg * 4 + j);
            #pragma unroll
            for (int dvt = 0; dvt < 4; dvt++)
                #pragma unroll
                for (int j = 0; j < 4; j++) O[dvt][j] *= a[j];
        }

        unsigned Pd[4][2];
        float rs = 0.f;
        #pragma unroll
        for (int t = 0; t < 4; t++) {
            float p0 = exp2f(S[t][0] - m);
            float p1 = exp2f(S[t][1] - m);
            float p2 = exp2f(S[t][2] - m);
            float p3 = exp2f(S[t][3] - m);
            rs += (p0 + p1) + (p2 + p3);
            Pd[t][0] = cvtpk_bf16(p0, p1);
            Pd[t][1] = cvtpk_bf16(p2, p3);
        }
        rs += __shfl_xor(rs, 16);
        rs += __shfl_xor(rs, 32);
        l += rs;
        #pragma unroll
        for (int t = 0; t < 4; t++) {
            u32x2 pw;
            pw[0] = Pd[t][0];
            pw[1] = Pd[t][1];
            int po = lr * 64 + (((2 * t + (lg >> 1)) ^ (lr & 7)) * 8) + (lg & 1) * 4;
            *(u32x2*)&Pl[wave][po] = pw;
        }

        __builtin_amdgcn_s_setprio(1);
        #pragma unroll
        for (int c2 = 0; c2 < 2; c2++) {
            bf16x8 pf = *(bf16x8*)&Pl[wave][lr * 64 + (((4 * c2 + lg) ^ (lr & 7)) * 8)];
            #pragma unroll
            for (int dvt = 0; dvt < 4; dvt++) {
                bf16x8 vf = *(bf16x8*)&Vt[(dvt * 16 + lr) * 64 + (((4 * c2 + lg) ^ (lr & 7)) * 8)];
                O[dvt] = __builtin_amdgcn_mfma_f32_16x16x32_bf16(pf, vf, O[dvt], 0, 0, 0);
            }
        }
        __builtin_amdgcn_s_setprio(0);
    }

    float linv = 1.f / l;
    float li[4];
    #pragma unroll
    for (int j = 0; j < 4; j++) li[j] = __shfl(linv, lg * 4 + j);
    #pragma unroll
    for (int dvt = 0; dvt < 4; dvt++) {
        #pragma unroll
        for (int j = 0; j < 4; j++) {
            int q = qb * 64 + wave * 16 + lg * 4 + j;
            int dv = dvt * 16 + lr;
            Fb[((size_t)(b * S_LEN + q)) * HID + h * HDIM + dv] =
                (short)f2bf(O[dvt][j] * li[j]);
        }
    }
}

// ------- gate GEMM (K=2048 over [xb | flowed]) + sigmoid + residual -----
// 64x64 tile, grid (64,16) = 1024 blocks = 4 blocks/CU; BK=64.
__global__ __launch_bounds__(256, 4)
void gemm_gate(const short* __restrict__ xb, const short* __restrict__ fb,
               const short* __restrict__ WgT, const float* __restrict__ bg,
               const float* __restrict__ x, float* __restrict__ y) {
    __shared__ short Al[2][64 * 32];
    __shared__ short Bl[2][64 * 32];
    int mb = blockIdx.x, nb = blockIdx.y;
    int tid = threadIdx.x;
    int wave = tid >> 6, lane = tid & 63;
    int wm = wave >> 1, wn = wave & 1;
    int lr = lane & 15, lg = lane >> 4;

    int r = tid >> 2;
    int c = tid & 3;
    int sc = (c ^ (r & 3)) * 8;
    int dst0 = tid * 8;
    size_t arow = (size_t)(mb * 64 + r) * 1024 + sc;
    const short* b0 = WgT + (size_t)(nb * 64 + r) * 2048 + sc;
    int fsw = (lg ^ (lr & 3)) * 8;

    f32x4 acc[2][2] = {};

    for (int ks = 0; ks < 32; ++ks) {
        int kg = ks * 64;
        const short* A = (kg < 1024) ? (xb + kg) : (fb + (kg - 1024));
        __syncthreads();
        gload16(A + arow, &Al[0][dst0]);
        gload16(A + arow + 32, &Al[1][dst0]);
        gload16(b0 + kg, &Bl[0][dst0]);
        gload16(b0 + kg + 32, &Bl[1][dst0]);
        __syncthreads();
        bf16x8 af[2][2], bfr[2][2];
        #pragma unroll
        for (int t = 0; t < 2; t++)
            #pragma unroll
            for (int s = 0; s < 2; s++) {
                af[t][s]  = *(bf16x8*)&Al[s][(wm * 32 + t * 16 + lr) * 32 + fsw];
                bfr[t][s] = *(bf16x8*)&Bl[s][(wn * 32 + t * 16 + lr) * 32 + fsw];
            }
        #pragma unroll
        for (int i = 0; i < 2; i++)
            #pragma unroll
            for (int jn = 0; jn < 2; jn++)
                #pragma unroll
                for (int s = 0; s < 2; s++)
                    acc[i][jn] = __builtin_amdgcn_mfma_f32_16x16x32_bf16(af[i][s], bfr[jn][s], acc[i][jn], 0, 0, 0);
    }

    #pragma unroll
    for (int jn = 0; jn < 2; jn++) {
        int n = nb * 64 + wn * 32 + jn * 16 + lr;
        float bgv = bg[n];
        #pragma unroll
        for (int i = 0; i < 2; i++) {
            #pragma unroll
            for (int j = 0; j < 4; j++) {
                int mm = mb * 64 + wm * 32 + i * 16 + lg * 4 + j;
                size_t idx = (size_t)mm * 1024 + n;
                float z = acc[i][jn][j] + bgv;
                float gate = 1.f / (1.f + __expf(-z));
                float fv = bf2f((unsigned short)fb[idx]);
                y[idx] = x[idx] + gate * fv;
            }
        }
    }
}

// ---------------- row LayerNorm in place (fp32 -> fp32) ----------------
__global__ __launch_bounds__(256)
void ln_kernel(float* __restrict__ y, const float* __restrict__ gamma,
               const float* __restrict__ beta) {
    int row = blockIdx.x;
    int tid = threadIdx.x;
    float4 v4 = *(const float4*)&y[(size_t)row * 1024 + tid * 4];
    float v[4] = {v4.x, v4.y, v4.z, v4.w};
    float s = v[0] + v[1] + v[2] + v[3];
    float s2 = v[0]*v[0] + v[1]*v[1] + v[2]*v[2] + v[3]*v[3];
    #pragma unroll
    for (int off = 1; off < 64; off <<= 1) {
        s += __shfl_xor(s, off);
        s2 += __shfl_xor(s2, off);
    }
    __shared__ float red[8];
    int wave = tid >> 6, lane = tid & 63;
    if (lane == 0) { red[wave] = s; red[4 + wave] = s2; }
    __syncthreads();
    s = red[0] + red[1] + red[2] + red[3];
    s2 = red[4] + red[5] + red[6] + red[7];
    float mu = s * (1.f / 1024.f);
    float var = s2 * (1.f / 1024.f) - mu * mu;
    float rsq = rsqrtf(var + 1e-5f);
    float4 o4;
    float* o = (float*)&o4;
    #pragma unroll
    for (int e = 0; e < 4; e++) {
        int n = tid * 4 + e;
        o[e] = (v[e] - mu) * rsq * gamma[n] + beta[n];
    }
    *(float4*)&y[(size_t)row * 1024 + tid * 4] = o4;
}

extern "C" void kernel_launch(void* const* d_in, const int* in_sizes, int n_in,
                              void* d_out, int out_size, void* d_ws, size_t ws_size,
                              hipStream_t stream) {
    const float* x     = (const float*)d_in[0];
    const float* Wq    = (const float*)d_in[1];
    const float* bq    = (const float*)d_in[2];
    const float* Wk    = (const float*)d_in[3];
    const float* bk    = (const float*)d_in[4];
    const float* Wv    = (const float*)d_in[5];
    const float* bv    = (const float*)d_in[6];
    const float* Wg    = (const float*)d_in[7];
    const float* bg    = (const float*)d_in[8];
    const float* gamma = (const float*)d_in[9];
    const float* beta  = (const float*)d_in[10];
    float* out = (float*)d_out;   // reference output is fp32

    char* w = (char*)d_ws;
    const size_t MB = 1024 * 1024;
    short* xb  = (short*)(w + 0 * MB);    // [4096][1024] bf16
    short* Qb  = (short*)(w + 8 * MB);    // pre-scaled by QSCALE
    short* Kb  = (short*)(w + 16 * MB);
    short* WT  = (short*)(w + 32 * MB);   // [3072][1024] bf16 (Wq^T|Wk^T|Wv^T)
    short* WgT = (short*)(w + 38 * MB);   // [1024][2048] bf16
    short* fb  = (short*)(w + 42 * MB);   // flowed bf16 [4096][1024]
    short* VT  = (short*)(w + 50 * MB);   // V^T per head [b*16+h][64 dv][2048 s]

    cvt_kernel<<<4096, 256, 0, stream>>>(x, xb, 4096 * 1024 / 4);
    dim3 tb(32, 8);
    transpose_all<<<dim3(32, 64, 4), tb, 0, stream>>>(Wq, Wk, Wv, Wg, WT, WgT);
    gemm_qkv<<<dim3(32, 24), 256, 0, stream>>>(xb, WT, bq, bk, bv, Qb, Kb, VT);
    attn_kernel<<<1024, 256, 0, stream>>>(Qb, Kb, VT, fb);
    gemm_gate<<<dim3(64, 16), 256, 0, stream>>>(xb, fb, WgT, bg, x, out);
    ln_kernel<<<4096, 256, 0, stream>>>(out, gamma, beta);
}